// Round 1
// baseline (285.470 us; speedup 1.0000x reference)
//
#include <hip/hip_runtime.h>

#define S_LEN 2048
#define D_DIM 1024
#define NH    16
#define DHEAD 64

typedef float f32x4 __attribute__((ext_vector_type(4)));
typedef __bf16 bf16x8 __attribute__((ext_vector_type(8)));
typedef unsigned short u16;
typedef unsigned short u16x8 __attribute__((ext_vector_type(8)));

__device__ __forceinline__ u16 f2bf(float f) {
    union { float f; unsigned u; } c; c.f = f;
    unsigned u = c.u + 0x7fffu + ((c.u >> 16) & 1u);
    return (u16)(u >> 16);
}
__device__ __forceinline__ float bf2f(u16 s) {
    union { float f; unsigned u; } c; c.u = ((unsigned)s) << 16; return c.f;
}

#define MFMA16(a, b, c) __builtin_amdgcn_mfma_f32_16x16x32_bf16((a), (b), (c), 0, 0, 0)

// ---------------------------------------------------------------------------
// M[h,j,f] = 0.125 * sum_e Wq[e, h*64+j] * Wv[e, h*64+f]
// grid 256 x 256 threads; lanes vary f -> Wv coalesced, Wq broadcast.
__global__ __launch_bounds__(256) void k_precomp_M(
    const float* __restrict__ Wq, const float* __restrict__ Wv, float* __restrict__ M) {
    int idx = blockIdx.x * 256 + threadIdx.x;      // 65536 = 16*64*64
    int h = idx >> 12, j = (idx >> 6) & 63, f = idx & 63;
    const float* q = Wq + h * DHEAD + j;
    const float* v = Wv + h * DHEAD + f;
    float acc = 0.f;
    for (int e = 0; e < D_DIM; ++e)
        acc += q[(size_t)e * D_DIM] * v[(size_t)e * D_DIM];
    M[idx] = acc * 0.125f;
}

// ---------------------------------------------------------------------------
// W2[o, h*64+j] = sum_f M[h,j,f] * Wout[o, h*64+f]   (bf16 out)
// block: 64 o-rows x one h. LDS-tiled for coalescing.
__global__ __launch_bounds__(256) void k_precomp_W2(
    const float* __restrict__ M, const float* __restrict__ Wout, u16* __restrict__ W2) {
    __shared__ float Ms[64][65];
    __shared__ float Ws[64][65];
    const int tid = threadIdx.x;
    const int ob = blockIdx.x, h = blockIdx.y;
    {
        int rr = tid >> 2, seg = tid & 3;
        const float* ms = M + ((size_t)(h * 64 + rr)) * 64 + seg * 16;
        const float* ws = Wout + (size_t)(ob * 64 + rr) * D_DIM + h * DHEAD + seg * 16;
#pragma unroll
        for (int e = 0; e < 16; ++e) {
            Ms[rr][seg * 16 + e] = ms[e];
            Ws[rr][seg * 16 + e] = ws[e];
        }
    }
    __syncthreads();
    int j = tid & 63, o0 = (tid >> 6) * 16;
    for (int oo = o0; oo < o0 + 16; ++oo) {
        float acc = 0.f;
#pragma unroll
        for (int f = 0; f < 64; ++f) acc += Ms[j][f] * Ws[oo][f];
        W2[(size_t)(ob * 64 + oo) * D_DIM + h * DHEAD + j] = f2bf(acc);
    }
}

// ---------------------------------------------------------------------------
// Q projection: Qbf[s, d] = bf16( sum_i x[s,i] * Wq[d,i] + bq[d] )
// 128x128 block tile, 4 waves 2x2, BK=32, mfma 16x16x32 bf16.
__global__ __launch_bounds__(256) void k_qproj(
    const float* __restrict__ x, const float* __restrict__ Wq,
    const float* __restrict__ bq, u16* __restrict__ Qbf) {
    __shared__ u16 Al[128][40];
    __shared__ u16 Bl[128][40];
    const int tid = threadIdx.x, lane = tid & 63, w = tid >> 6;
    const int wm = w & 1, wn = w >> 1;
    const int col16 = lane & 15, quad = lane >> 4;
    const int bm = blockIdx.x, bn = blockIdx.y;

    f32x4 acc[4][4];
    const f32x4 z4 = {0.f, 0.f, 0.f, 0.f};
#pragma unroll
    for (int i = 0; i < 4; ++i)
#pragma unroll
        for (int j = 0; j < 4; ++j) acc[i][j] = z4;

    const int r = tid >> 1, hf = tid & 1;
    const float* pa = x + (size_t)(bm * 128 + r) * D_DIM + hf * 16;
    const float* pb = Wq + (size_t)(bn * 128 + r) * D_DIM + hf * 16;

    for (int k0 = 0; k0 < D_DIM; k0 += 32) {
        u16x8 wa0, wa1, wb0, wb1;
        {
            f32x4 a0 = *(const f32x4*)(pa + k0);
            f32x4 a1 = *(const f32x4*)(pa + k0 + 4);
            f32x4 a2 = *(const f32x4*)(pa + k0 + 8);
            f32x4 a3 = *(const f32x4*)(pa + k0 + 12);
            f32x4 b0 = *(const f32x4*)(pb + k0);
            f32x4 b1 = *(const f32x4*)(pb + k0 + 4);
            f32x4 b2 = *(const f32x4*)(pb + k0 + 8);
            f32x4 b3 = *(const f32x4*)(pb + k0 + 12);
#pragma unroll
            for (int e = 0; e < 4; ++e) {
                wa0[e] = f2bf(a0[e]); wa0[e + 4] = f2bf(a1[e]);
                wa1[e] = f2bf(a2[e]); wa1[e + 4] = f2bf(a3[e]);
                wb0[e] = f2bf(b0[e]); wb0[e + 4] = f2bf(b1[e]);
                wb1[e] = f2bf(b2[e]); wb1[e + 4] = f2bf(b3[e]);
            }
        }
        __syncthreads();
        *(u16x8*)&Al[r][hf * 16]     = wa0;
        *(u16x8*)&Al[r][hf * 16 + 8] = wa1;
        *(u16x8*)&Bl[r][hf * 16]     = wb0;
        *(u16x8*)&Bl[r][hf * 16 + 8] = wb1;
        __syncthreads();

        bf16x8 af[4];
#pragma unroll
        for (int mt = 0; mt < 4; ++mt)
            af[mt] = *(const bf16x8*)&Al[wm * 64 + mt * 16 + col16][quad * 8];
#pragma unroll
        for (int nt = 0; nt < 4; ++nt) {
            bf16x8 bfr = *(const bf16x8*)&Bl[wn * 64 + nt * 16 + col16][quad * 8];
#pragma unroll
            for (int mt = 0; mt < 4; ++mt)
                acc[mt][nt] = MFMA16(af[mt], bfr, acc[mt][nt]);
        }
    }
#pragma unroll
    for (int nt = 0; nt < 4; ++nt) {
        int col = bn * 128 + wn * 64 + nt * 16 + col16;
        float bqv = bq[col];
#pragma unroll
        for (int mt = 0; mt < 4; ++mt) {
            int row0 = bm * 128 + wm * 64 + mt * 16 + quad * 4;
#pragma unroll
            for (int rr = 0; rr < 4; ++rr)
                Qbf[(size_t)(row0 + rr) * D_DIM + col] = f2bf(acc[mt][nt][rr] + bqv);
        }
    }
}

// ---------------------------------------------------------------------------
// Fused L2 attention (no-rescale streaming softmax; z <= ||q_s||^2/8, no overflow).
// Block = (b, h, q-tile of 128). 4 waves, each 32 q-rows x 128 k-cols.
__global__ __launch_bounds__(256) void k_flash(
    const u16* __restrict__ Qbf, const int* __restrict__ mask, u16* __restrict__ attnO) {
    __shared__ u16 Qt[128][72];
    __shared__ u16 Kt[128][72];
    __shared__ u16 KtT[64][136];
    __shared__ u16 Ptw[4][32][40];
    __shared__ float sqm[128];

    const int tid = threadIdx.x, lane = tid & 63, w = tid >> 6;
    const int col16 = lane & 15, quad = lane >> 4;
    const int qt = blockIdx.x & 15;
    const int h = (blockIdx.x >> 4) & 15;
    const int b = blockIdx.x >> 8;
    const u16* qbase = Qbf + (size_t)b * S_LEN * D_DIM + h * DHEAD;

    // stage Q tile once
    if (tid < 128) {
        const u16* src = qbase + (size_t)(qt * 128 + tid) * D_DIM;
#pragma unroll
        for (int i = 0; i < 8; ++i)
            *(u16x8*)&Qt[tid][i * 8] = *(const u16x8*)(src + i * 8);
    }

    f32x4 Oacc[2][4];
    float lsum[2][4];
    const f32x4 z4 = {0.f, 0.f, 0.f, 0.f};
#pragma unroll
    for (int m = 0; m < 2; ++m)
#pragma unroll
        for (int i = 0; i < 4; ++i) { Oacc[m][i] = z4; lsum[m][i] = 0.f; }

    for (int j = 0; j < S_LEN / 128; ++j) {
        u16x8 v[8];
        const bool stager = tid < 128;
        if (stager) {
            const u16* src = qbase + (size_t)(j * 128 + tid) * D_DIM;
#pragma unroll
            for (int i = 0; i < 8; ++i) v[i] = *(const u16x8*)(src + i * 8);
        }
        __syncthreads();   // prior iteration's LDS reads done
        if (stager) {
            float ss = 0.f;
#pragma unroll
            for (int i = 0; i < 8; ++i) {
                *(u16x8*)&Kt[tid][i * 8] = v[i];
#pragma unroll
                for (int e = 0; e < 8; ++e) {
                    float fv = bf2f(v[i][e]);
                    ss += fv * fv;
                    KtT[i * 8 + e][tid] = v[i][e];
                }
            }
            sqm[tid] = mask[b * S_LEN + j * 128 + tid] ? ss : 7.2e16f;
        }
        __syncthreads();

        // S = Q K^T  (per wave: 32 x 128, K=64)
        f32x4 sacc[2][8];
#pragma unroll
        for (int m = 0; m < 2; ++m)
#pragma unroll
            for (int n = 0; n < 8; ++n) sacc[m][n] = z4;
#pragma unroll
        for (int k0 = 0; k0 < 2; ++k0) {
            bf16x8 a0 = *(const bf16x8*)&Qt[w * 32 + col16][k0 * 32 + quad * 8];
            bf16x8 a1 = *(const bf16x8*)&Qt[w * 32 + 16 + col16][k0 * 32 + quad * 8];
#pragma unroll
            for (int n = 0; n < 8; ++n) {
                bf16x8 bb = *(const bf16x8*)&Kt[n * 16 + col16][k0 * 32 + quad * 8];
                sacc[0][n] = MFMA16(a0, bb, sacc[0][n]);
                sacc[1][n] = MFMA16(a1, bb, sacc[1][n]);
            }
        }
        float sq8[8];
#pragma unroll
        for (int n = 0; n < 8; ++n) sq8[n] = sqm[n * 16 + col16] * 0.125f;

        // P = exp(z), chunked LDS round-trip + PV mfma
#pragma unroll
        for (int kt = 0; kt < 4; ++kt) {
#pragma unroll
            for (int m = 0; m < 2; ++m)
#pragma unroll
                for (int nn = 0; nn < 2; ++nn) {
                    int n = kt * 2 + nn;
#pragma unroll
                    for (int rr = 0; rr < 4; ++rr) {
                        float p = __expf(sacc[m][n][rr] * 0.25f - sq8[n]);
                        lsum[m][rr] += p;
                        Ptw[w][m * 16 + quad * 4 + rr][nn * 16 + col16] = f2bf(p);
                    }
                }
            bf16x8 pa0 = *(const bf16x8*)&Ptw[w][col16][quad * 8];
            bf16x8 pa1 = *(const bf16x8*)&Ptw[w][16 + col16][quad * 8];
#pragma unroll
            for (int no = 0; no < 4; ++no) {
                bf16x8 vb = *(const bf16x8*)&KtT[no * 16 + col16][kt * 32 + quad * 8];
                Oacc[0][no] = MFMA16(pa0, vb, Oacc[0][no]);
                Oacc[1][no] = MFMA16(pa1, vb, Oacc[1][no]);
            }
        }
    }

    // finalize: full row-sum across the 16-lane group, O /= l, store bf16
#pragma unroll
    for (int m = 0; m < 2; ++m)
#pragma unroll
        for (int rr = 0; rr < 4; ++rr) {
            float l = lsum[m][rr];
#pragma unroll
            for (int off = 1; off < 16; off <<= 1) l += __shfl_xor(l, off, 64);
            lsum[m][rr] = 1.f / l;
        }
    u16* obase = attnO + (size_t)b * S_LEN * D_DIM + h * DHEAD;
#pragma unroll
    for (int m = 0; m < 2; ++m)
#pragma unroll
        for (int no = 0; no < 4; ++no)
#pragma unroll
            for (int rr = 0; rr < 4; ++rr) {
                int srow = qt * 128 + w * 32 + m * 16 + quad * 4 + rr;
                obase[(size_t)srow * D_DIM + no * 16 + col16] =
                    f2bf(Oacc[m][no][rr] * lsum[m][rr]);
            }
}

// ---------------------------------------------------------------------------
// Output GEMM: out[s,o] = x[s,o] + bout[o] + sum_c attnO[s,c] * W2[o,c]
__global__ __launch_bounds__(256) void k_oproj(
    const u16* __restrict__ attnO, const u16* __restrict__ W2,
    const float* __restrict__ x, const float* __restrict__ bout, float* __restrict__ out) {
    __shared__ u16 Al[128][40];
    __shared__ u16 Bl[128][40];
    const int tid = threadIdx.x, lane = tid & 63, w = tid >> 6;
    const int wm = w & 1, wn = w >> 1;
    const int col16 = lane & 15, quad = lane >> 4;
    const int bm = blockIdx.x, bn = blockIdx.y;

    f32x4 acc[4][4];
    const f32x4 z4 = {0.f, 0.f, 0.f, 0.f};
#pragma unroll
    for (int i = 0; i < 4; ++i)
#pragma unroll
        for (int j = 0; j < 4; ++j) acc[i][j] = z4;

    const int r = tid >> 1, hf = tid & 1;
    const u16* pa = attnO + (size_t)(bm * 128 + r) * D_DIM + hf * 16;
    const u16* pb = W2 + (size_t)(bn * 128 + r) * D_DIM + hf * 16;

    for (int k0 = 0; k0 < D_DIM; k0 += 32) {
        u16x8 wa0 = *(const u16x8*)(pa + k0);
        u16x8 wa1 = *(const u16x8*)(pa + k0 + 8);
        u16x8 wb0 = *(const u16x8*)(pb + k0);
        u16x8 wb1 = *(const u16x8*)(pb + k0 + 8);
        __syncthreads();
        *(u16x8*)&Al[r][hf * 16]     = wa0;
        *(u16x8*)&Al[r][hf * 16 + 8] = wa1;
        *(u16x8*)&Bl[r][hf * 16]     = wb0;
        *(u16x8*)&Bl[r][hf * 16 + 8] = wb1;
        __syncthreads();

        bf16x8 af[4];
#pragma unroll
        for (int mt = 0; mt < 4; ++mt)
            af[mt] = *(const bf16x8*)&Al[wm * 64 + mt * 16 + col16][quad * 8];
#pragma unroll
        for (int nt = 0; nt < 4; ++nt) {
            bf16x8 bfr = *(const bf16x8*)&Bl[wn * 64 + nt * 16 + col16][quad * 8];
#pragma unroll
            for (int mt = 0; mt < 4; ++mt)
                acc[mt][nt] = MFMA16(af[mt], bfr, acc[mt][nt]);
        }
    }
#pragma unroll
    for (int nt = 0; nt < 4; ++nt) {
        int col = bn * 128 + wn * 64 + nt * 16 + col16;
        float bv = bout[col];
#pragma unroll
        for (int mt = 0; mt < 4; ++mt) {
            int row0 = bm * 128 + wm * 64 + mt * 16 + quad * 4;
#pragma unroll
            for (int rr = 0; rr < 4; ++rr) {
                size_t idx = (size_t)(row0 + rr) * D_DIM + col;
                out[idx] = acc[mt][nt][rr] + x[idx] + bv;
            }
        }
    }
}

// ---------------------------------------------------------------------------
extern "C" void kernel_launch(void* const* d_in, const int* in_sizes, int n_in,
                              void* d_out, int out_size, void* d_ws, size_t ws_size,
                              hipStream_t stream) {
    const float* x    = (const float*)d_in[0];
    const float* Wq   = (const float*)d_in[1];
    const float* bq   = (const float*)d_in[2];
    const float* Wv   = (const float*)d_in[3];
    const float* Wout = (const float*)d_in[4];
    const float* bout = (const float*)d_in[5];
    const int*   mask = (const int*)d_in[6];
    float* out = (float*)d_out;

    char* ws = (char*)d_ws;
    u16*   Qbf   = (u16*)(ws);                       // 8 MB
    u16*   attnO = (u16*)(ws + (8u << 20));          // 8 MB
    u16*   W2    = (u16*)(ws + (16u << 20));         // 2 MB
    float* Mbuf  = (float*)(ws + (18u << 20));       // 256 KB

    k_precomp_M<<<dim3(256), dim3(256), 0, stream>>>(Wq, Wv, Mbuf);
    k_precomp_W2<<<dim3(16, 16), dim3(256), 0, stream>>>(Mbuf, Wout, W2);
    k_qproj<<<dim3(32, 8), dim3(256), 0, stream>>>(x, Wq, bq, Qbf);
    k_flash<<<dim3(512), dim3(256), 0, stream>>>(Qbf, mask, attnO);
    k_oproj<<<dim3(32, 8), dim3(256), 0, stream>>>(attnO, W2, x, bout, out);
}

// Round 2
// 251.992 us; speedup vs baseline: 1.1329x; 1.1329x over previous
//
#include <hip/hip_runtime.h>

#define S_LEN 2048
#define D_DIM 1024
#define NH    16
#define DHEAD 64

typedef float f32x4 __attribute__((ext_vector_type(4)));
typedef __bf16 bf16x8 __attribute__((ext_vector_type(8)));
typedef unsigned short u16;
typedef unsigned short u16x8 __attribute__((ext_vector_type(8)));
typedef unsigned short u16x4 __attribute__((ext_vector_type(4)));

__device__ __forceinline__ u16 f2bf(float f) {
    union { float f; unsigned u; } c; c.f = f;
    unsigned u = c.u + 0x7fffu + ((c.u >> 16) & 1u);
    return (u16)(u >> 16);
}

#define MFMA16(a, b, c) __builtin_amdgcn_mfma_f32_16x16x32_bf16((a), (b), (c), 0, 0, 0)

// ---------------------------------------------------------------------------
// M[h,j,f] = 0.125 * sum_e Wq[e, h*64+j] * Wv[e, h*64+f]
// grid (64 j, 16 h); 256 threads: f = tid&63, K split 4-ways (ks = tid>>6).
__global__ __launch_bounds__(256) void k_precomp_M(
    const float* __restrict__ Wq, const float* __restrict__ Wv, float* __restrict__ M) {
    __shared__ float red[4][64];
    const int tid = threadIdx.x;
    const int f = tid & 63, ks = tid >> 6;
    const int j = blockIdx.x, h = blockIdx.y;
    const float* q = Wq + h * DHEAD + j;
    const float* v = Wv + h * DHEAD + f;
    float acc = 0.f;
    const int e0 = ks * 256;
#pragma unroll 8
    for (int e = e0; e < e0 + 256; ++e)
        acc += q[(size_t)e * D_DIM] * v[(size_t)e * D_DIM];
    red[ks][f] = acc;
    __syncthreads();
    if (ks == 0) {
        float s = red[0][f] + red[1][f] + red[2][f] + red[3][f];
        M[((size_t)(h * 64 + j)) * 64 + f] = s * 0.125f;
    }
}

// ---------------------------------------------------------------------------
// W2[o, h*64+j] = sum_f M[h,j,f] * Wout[o, h*64+f]   (bf16 out)
__global__ __launch_bounds__(256) void k_precomp_W2(
    const float* __restrict__ M, const float* __restrict__ Wout, u16* __restrict__ W2) {
    __shared__ float Ms[64][65];
    __shared__ float Ws[64][65];
    const int tid = threadIdx.x;
    const int ob = blockIdx.x, h = blockIdx.y;
    {
        int rr = tid >> 2, seg = tid & 3;
        const float* ms = M + ((size_t)(h * 64 + rr)) * 64 + seg * 16;
        const float* ws = Wout + (size_t)(ob * 64 + rr) * D_DIM + h * DHEAD + seg * 16;
#pragma unroll
        for (int e = 0; e < 16; ++e) {
            Ms[rr][seg * 16 + e] = ms[e];
            Ws[rr][seg * 16 + e] = ws[e];
        }
    }
    __syncthreads();
    int j = tid & 63, o0 = (tid >> 6) * 16;
    for (int oo = o0; oo < o0 + 16; ++oo) {
        float acc = 0.f;
#pragma unroll
        for (int f = 0; f < 64; ++f) acc += Ms[j][f] * Ws[oo][f];
        W2[(size_t)(ob * 64 + oo) * D_DIM + h * DHEAD + j] = f2bf(acc);
    }
}

// ---------------------------------------------------------------------------
// Q projection + epilogue side-products:
//   Qbf[s,d] = bf16(q), QT[b,h,d,s] = bf16(q), sq05[b,h,s] = 0.125*||q_h||^2 (mask->1e30)
__global__ __launch_bounds__(256) void k_qproj(
    const float* __restrict__ x, const float* __restrict__ Wq,
    const float* __restrict__ bq, const int* __restrict__ mask,
    u16* __restrict__ Qbf, u16* __restrict__ QT, float* __restrict__ sq05) {
    __shared__ u16 Al[128][40];
    __shared__ u16 Bl[128][40];
    const int tid = threadIdx.x, lane = tid & 63, w = tid >> 6;
    const int wm = w & 1, wn = w >> 1;
    const int col16 = lane & 15, quad = lane >> 4;
    const int bm = blockIdx.x, bn = blockIdx.y;

    f32x4 acc[4][4];
    const f32x4 z4 = {0.f, 0.f, 0.f, 0.f};
#pragma unroll
    for (int i = 0; i < 4; ++i)
#pragma unroll
        for (int j = 0; j < 4; ++j) acc[i][j] = z4;

    const int r = tid >> 1, hf = tid & 1;
    const float* pa = x + (size_t)(bm * 128 + r) * D_DIM + hf * 16;
    const float* pb = Wq + (size_t)(bn * 128 + r) * D_DIM + hf * 16;

    for (int k0 = 0; k0 < D_DIM; k0 += 32) {
        u16x8 wa0, wa1, wb0, wb1;
        {
            f32x4 a0 = *(const f32x4*)(pa + k0);
            f32x4 a1 = *(const f32x4*)(pa + k0 + 4);
            f32x4 a2 = *(const f32x4*)(pa + k0 + 8);
            f32x4 a3 = *(const f32x4*)(pa + k0 + 12);
            f32x4 b0 = *(const f32x4*)(pb + k0);
            f32x4 b1 = *(const f32x4*)(pb + k0 + 4);
            f32x4 b2 = *(const f32x4*)(pb + k0 + 8);
            f32x4 b3 = *(const f32x4*)(pb + k0 + 12);
#pragma unroll
            for (int e = 0; e < 4; ++e) {
                wa0[e] = f2bf(a0[e]); wa0[e + 4] = f2bf(a1[e]);
                wa1[e] = f2bf(a2[e]); wa1[e + 4] = f2bf(a3[e]);
                wb0[e] = f2bf(b0[e]); wb0[e + 4] = f2bf(b1[e]);
                wb1[e] = f2bf(b2[e]); wb1[e + 4] = f2bf(b3[e]);
            }
        }
        __syncthreads();
        *(u16x8*)&Al[r][hf * 16]     = wa0;
        *(u16x8*)&Al[r][hf * 16 + 8] = wa1;
        *(u16x8*)&Bl[r][hf * 16]     = wb0;
        *(u16x8*)&Bl[r][hf * 16 + 8] = wb1;
        __syncthreads();

        bf16x8 af[4];
#pragma unroll
        for (int mt = 0; mt < 4; ++mt)
            af[mt] = *(const bf16x8*)&Al[wm * 64 + mt * 16 + col16][quad * 8];
#pragma unroll
        for (int nt = 0; nt < 4; ++nt) {
            bf16x8 bfr = *(const bf16x8*)&Bl[wn * 64 + nt * 16 + col16][quad * 8];
#pragma unroll
            for (int mt = 0; mt < 4; ++mt)
                acc[mt][nt] = MFMA16(af[mt], bfr, acc[mt][nt]);
        }
    }

    const int h = bn * 2 + wn;                   // head this wave's cols belong to
    f32x4 ssum[4];
#pragma unroll
    for (int mt = 0; mt < 4; ++mt) ssum[mt] = z4;

#pragma unroll
    for (int nt = 0; nt < 4; ++nt) {
        int col = bn * 128 + wn * 64 + nt * 16 + col16;
        int dloc = nt * 16 + col16;
        float bqv = bq[col];
#pragma unroll
        for (int mt = 0; mt < 4; ++mt) {
            int row0 = bm * 128 + wm * 64 + mt * 16 + quad * 4;
            int b = row0 >> 11, smod0 = row0 & 2047;
            u16x4 pk;
#pragma unroll
            for (int rr = 0; rr < 4; ++rr) {
                float qv = acc[mt][nt][rr] + bqv;
                ssum[mt][rr] += qv * qv;
                u16 bv = f2bf(qv);
                pk[rr] = bv;
                Qbf[(size_t)(row0 + rr) * D_DIM + col] = bv;
            }
            *(u16x4*)(QT + ((size_t)(b * NH + h) * DHEAD + dloc) * S_LEN + smod0) = pk;
        }
    }
    // reduce ||q||^2 across the 16-lane col group, write sq05 (mask-folded)
#pragma unroll
    for (int mt = 0; mt < 4; ++mt) {
        int row0 = bm * 128 + wm * 64 + mt * 16 + quad * 4;
        int b = row0 >> 11, smod0 = row0 & 2047;
#pragma unroll
        for (int rr = 0; rr < 4; ++rr) {
            float v = ssum[mt][rr];
            v += __shfl_xor(v, 1); v += __shfl_xor(v, 2);
            v += __shfl_xor(v, 4); v += __shfl_xor(v, 8);
            if (col16 == 0) {
                int sidx = smod0 + rr;
                float out = mask[b * S_LEN + sidx] ? v * 0.125f : 1e30f;
                sq05[((size_t)(b * NH + h)) * S_LEN + sidx] = out;
            }
        }
    }
}

// ---------------------------------------------------------------------------
// Fused L2 attention. Block = (b, h, q-tile 128). 4 waves x (32 q-rows, 128 k).
// Q a-frags in registers; K staged both orientations by all 256 threads with
// register prefetch of tile j+1; row-sums via MFMA with ones-fragment.
__global__ __launch_bounds__(256, 2) void k_flash(
    const u16* __restrict__ Qbf, const u16* __restrict__ QT,
    const float* __restrict__ sq05, u16* __restrict__ attnO) {
    __shared__ u16 Kt[128][72];
    __shared__ u16 KtT[64][136];
    __shared__ u16 Ptw[4][32][36];
    __shared__ float sql[128];

    const int tid = threadIdx.x, lane = tid & 63, w = tid >> 6;
    const int col16 = lane & 15, quad = lane >> 4;
    const int qt = blockIdx.x & 15;
    const int h = (blockIdx.x >> 4) & 15;
    const int b = blockIdx.x >> 8;
    const u16* qbase = Qbf + (size_t)b * S_LEN * D_DIM + h * DHEAD;
    const u16* qtbase = QT + ((size_t)(b * NH + h)) * DHEAD * S_LEN;
    const float* sqb = sq05 + ((size_t)(b * NH + h)) * S_LEN;

    // loop-invariant Q a-fragments, straight from global
    bf16x8 af[2][2];
#pragma unroll
    for (int mt = 0; mt < 2; ++mt)
#pragma unroll
        for (int k0 = 0; k0 < 2; ++k0)
            af[mt][k0] = *(const bf16x8*)(qbase +
                (size_t)(qt * 128 + w * 32 + mt * 16 + col16) * D_DIM + k0 * 32 + quad * 8);

    // staging assignments (all 256 threads)
    const int kr = tid >> 1, ks = tid & 1;         // Kt: row, 32-u16 half
    const int td = tid >> 2, ts = tid & 3;         // KtT: d-row, 32-u16 quarter
    const u16* ksrc = qbase + (size_t)kr * D_DIM + ks * 32;
    const u16* tsrc = qtbase + (size_t)td * S_LEN + ts * 32;

    u16x8 pk[4], pt[4];
    float sv = 0.f;
    {
#pragma unroll
        for (int i = 0; i < 4; ++i) pk[i] = *(const u16x8*)(ksrc + i * 8);
#pragma unroll
        for (int i = 0; i < 4; ++i) pt[i] = *(const u16x8*)(tsrc + i * 8);
        if (tid < 128) sv = sqb[tid];
    }

    f32x4 Oacc[2][4], lacc[2];
    const f32x4 z4 = {0.f, 0.f, 0.f, 0.f};
#pragma unroll
    for (int m = 0; m < 2; ++m) {
        lacc[m] = z4;
#pragma unroll
        for (int i = 0; i < 4; ++i) Oacc[m][i] = z4;
    }
    bf16x8 ones;
    {
        union { u16x8 u; bf16x8 b; } cv;
#pragma unroll
        for (int e = 0; e < 8; ++e) cv.u[e] = 0x3F80;
        ones = cv.b;
    }

    for (int j = 0; j < S_LEN / 128; ++j) {
        __syncthreads();          // prior iteration's LDS reads complete
#pragma unroll
        for (int i = 0; i < 4; ++i) *(u16x8*)&Kt[kr][ks * 32 + i * 8] = pk[i];
#pragma unroll
        for (int i = 0; i < 4; ++i) *(u16x8*)&KtT[td][ts * 32 + i * 8] = pt[i];
        if (tid < 128) sql[tid] = sv;
        __syncthreads();          // tile visible

        // prefetch next tile into registers (overlaps with compute below)
        int jn = (j + 1) & 15;
        {
            const u16* kn = ksrc + (size_t)jn * 128 * D_DIM;
            const u16* tn = tsrc + (size_t)jn * 128;
#pragma unroll
            for (int i = 0; i < 4; ++i) pk[i] = *(const u16x8*)(kn + i * 8);
#pragma unroll
            for (int i = 0; i < 4; ++i) pt[i] = *(const u16x8*)(tn + i * 8);
            if (tid < 128) sv = sqb[jn * 128 + tid];
        }

        // S = Q K^T : per wave 32 x 128, K = 64
        f32x4 sacc[2][8];
#pragma unroll
        for (int m = 0; m < 2; ++m)
#pragma unroll
            for (int n = 0; n < 8; ++n) sacc[m][n] = z4;
#pragma unroll
        for (int k0 = 0; k0 < 2; ++k0) {
#pragma unroll
            for (int n = 0; n < 8; ++n) {
                bf16x8 bb = *(const bf16x8*)&Kt[n * 16 + col16][k0 * 32 + quad * 8];
                sacc[0][n] = MFMA16(af[0][k0], bb, sacc[0][n]);
                sacc[1][n] = MFMA16(af[1][k0], bb, sacc[1][n]);
            }
        }
        float sq2[8];
#pragma unroll
        for (int n = 0; n < 8; ++n) sq2[n] = sql[n * 16 + col16];

        // P = exp(qk*0.25 - sq05), chunked LDS round-trip + PV + row-sum MFMA
#pragma unroll
        for (int kt = 0; kt < 4; ++kt) {
#pragma unroll
            for (int m = 0; m < 2; ++m)
#pragma unroll
                for (int nn = 0; nn < 2; ++nn) {
                    int n = kt * 2 + nn;
#pragma unroll
                    for (int rr = 0; rr < 4; ++rr) {
                        float p = __expf(fmaf(sacc[m][n][rr], 0.25f, -sq2[n]));
                        Ptw[w][m * 16 + quad * 4 + rr][nn * 16 + col16] = f2bf(p);
                    }
                }
            bf16x8 pa0 = *(const bf16x8*)&Ptw[w][col16][quad * 8];
            bf16x8 pa1 = *(const bf16x8*)&Ptw[w][16 + col16][quad * 8];
            lacc[0] = MFMA16(pa0, ones, lacc[0]);
            lacc[1] = MFMA16(pa1, ones, lacc[1]);
#pragma unroll
            for (int no = 0; no < 4; ++no) {
                bf16x8 vb = *(const bf16x8*)&KtT[no * 16 + col16][kt * 32 + quad * 8];
                Oacc[0][no] = MFMA16(pa0, vb, Oacc[0][no]);
                Oacc[1][no] = MFMA16(pa1, vb, Oacc[1][no]);
            }
        }
    }

    // epilogue: O /= rowsum (rowsum broadcast in every lacc column), store bf16
    u16* obase = attnO + (size_t)b * S_LEN * D_DIM + h * DHEAD;
#pragma unroll
    for (int m = 0; m < 2; ++m) {
        f32x4 rinv;
#pragma unroll
        for (int rr = 0; rr < 4; ++rr) rinv[rr] = 1.f / lacc[m][rr];
#pragma unroll
        for (int no = 0; no < 4; ++no)
#pragma unroll
            for (int rr = 0; rr < 4; ++rr) {
                int srow = qt * 128 + w * 32 + m * 16 + quad * 4 + rr;
                obase[(size_t)srow * D_DIM + no * 16 + col16] =
                    f2bf(Oacc[m][no][rr] * rinv[rr]);
            }
    }
}

// ---------------------------------------------------------------------------
// Output GEMM: out[s,o] = x[s,o] + bout[o] + sum_c attnO[s,c] * W2[o,c]
__global__ __launch_bounds__(256) void k_oproj(
    const u16* __restrict__ attnO, const u16* __restrict__ W2,
    const float* __restrict__ x, const float* __restrict__ bout, float* __restrict__ out) {
    __shared__ u16 Al[128][40];
    __shared__ u16 Bl[128][40];
    const int tid = threadIdx.x, lane = tid & 63, w = tid >> 6;
    const int wm = w & 1, wn = w >> 1;
    const int col16 = lane & 15, quad = lane >> 4;
    const int bm = blockIdx.x, bn = blockIdx.y;

    f32x4 acc[4][4];
    const f32x4 z4 = {0.f, 0.f, 0.f, 0.f};
#pragma unroll
    for (int i = 0; i < 4; ++i)
#pragma unroll
        for (int j = 0; j < 4; ++j) acc[i][j] = z4;

    const int r = tid >> 1, hf = tid & 1;
    const u16* pa = attnO + (size_t)(bm * 128 + r) * D_DIM + hf * 16;
    const u16* pb = W2 + (size_t)(bn * 128 + r) * D_DIM + hf * 16;

    for (int k0 = 0; k0 < D_DIM; k0 += 32) {
        u16x8 wa0 = *(const u16x8*)(pa + k0);
        u16x8 wa1 = *(const u16x8*)(pa + k0 + 8);
        u16x8 wb0 = *(const u16x8*)(pb + k0);
        u16x8 wb1 = *(const u16x8*)(pb + k0 + 8);
        __syncthreads();
        *(u16x8*)&Al[r][hf * 16]     = wa0;
        *(u16x8*)&Al[r][hf * 16 + 8] = wa1;
        *(u16x8*)&Bl[r][hf * 16]     = wb0;
        *(u16x8*)&Bl[r][hf * 16 + 8] = wb1;
        __syncthreads();

        bf16x8 af[4];
#pragma unroll
        for (int mt = 0; mt < 4; ++mt)
            af[mt] = *(const bf16x8*)&Al[wm * 64 + mt * 16 + col16][quad * 8];
#pragma unroll
        for (int nt = 0; nt < 4; ++nt) {
            bf16x8 bfr = *(const bf16x8*)&Bl[wn * 64 + nt * 16 + col16][quad * 8];
#pragma unroll
            for (int mt = 0; mt < 4; ++mt)
                acc[mt][nt] = MFMA16(af[mt], bfr, acc[mt][nt]);
        }
    }
#pragma unroll
    for (int nt = 0; nt < 4; ++nt) {
        int col = bn * 128 + wn * 64 + nt * 16 + col16;
        float bv = bout[col];
#pragma unroll
        for (int mt = 0; mt < 4; ++mt) {
            int row0 = bm * 128 + wm * 64 + mt * 16 + quad * 4;
#pragma unroll
            for (int rr = 0; rr < 4; ++rr) {
                size_t idx = (size_t)(row0 + rr) * D_DIM + col;
                out[idx] = acc[mt][nt][rr] + x[idx] + bv;
            }
        }
    }
}

// ---------------------------------------------------------------------------
extern "C" void kernel_launch(void* const* d_in, const int* in_sizes, int n_in,
                              void* d_out, int out_size, void* d_ws, size_t ws_size,
                              hipStream_t stream) {
    const float* x    = (const float*)d_in[0];
    const float* Wq   = (const float*)d_in[1];
    const float* bq   = (const float*)d_in[2];
    const float* Wv   = (const float*)d_in[3];
    const float* Wout = (const float*)d_in[4];
    const float* bout = (const float*)d_in[5];
    const int*   mask = (const int*)d_in[6];
    float* out = (float*)d_out;

    char* ws = (char*)d_ws;
    u16*   Qbf   = (u16*)(ws);                         // 8 MB
    u16*   QT    = (u16*)(ws + (8u << 20));            // 8 MB
    u16*   attnO = (u16*)(ws + (16u << 20));           // 8 MB
    u16*   W2    = (u16*)(ws + (24u << 20));           // 2 MB
    float* Mbuf  = (float*)(ws + (26u << 20));         // 256 KB
    float* sq05  = (float*)(ws + (26u << 20) + (256u << 10)); // 256 KB

    k_precomp_M<<<dim3(64, 16), dim3(256), 0, stream>>>(Wq, Wv, Mbuf);
    k_precomp_W2<<<dim3(16, 16), dim3(256), 0, stream>>>(Mbuf, Wout, W2);
    k_qproj<<<dim3(32, 8), dim3(256), 0, stream>>>(x, Wq, bq, mask, Qbf, QT, sq05);
    k_flash<<<dim3(512), dim3(256), 0, stream>>>(Qbf, QT, sq05, attnO);
    k_oproj<<<dim3(32, 8), dim3(256), 0, stream>>>(attnO, W2, x, bout, out);
}

// Round 3
// 241.921 us; speedup vs baseline: 1.1800x; 1.0416x over previous
//
#include <hip/hip_runtime.h>

#define S_LEN 2048
#define D_DIM 1024
#define NH    16
#define DHEAD 64

typedef float f32x4 __attribute__((ext_vector_type(4)));
typedef __bf16 bf16x8 __attribute__((ext_vector_type(8)));
typedef unsigned short u16;
typedef unsigned short u16x8 __attribute__((ext_vector_type(8)));
typedef unsigned short u16x4 __attribute__((ext_vector_type(4)));

__device__ __forceinline__ u16 f2bf(float f) {
    union { float f; unsigned u; } c; c.f = f;
    unsigned u = c.u + 0x7fffu + ((c.u >> 16) & 1u);
    return (u16)(u >> 16);
}

#if __has_builtin(__builtin_amdgcn_exp2f)
#define EXP2(x) __builtin_amdgcn_exp2f(x)
#else
#define EXP2(x) exp2f(x)
#endif

// 0.25*log2(e), 0.125*log2(e)
#define C_QK  0.36067376022224085f
#define C_SQ  0.18033688011112043f

#define MFMA16(a, b, c) __builtin_amdgcn_mfma_f32_16x16x32_bf16((a), (b), (c), 0, 0, 0)

// ---------------------------------------------------------------------------
// Convert x (4.19M) and Wq (1.05M) fp32 -> bf16 once. 8 elems/thread.
__global__ __launch_bounds__(256) void k_cvt(
    const float* __restrict__ x, const float* __restrict__ wq,
    u16* __restrict__ xb, u16* __restrict__ wqb) {
    const int bid = blockIdx.x;
    const float* s; u16* d; size_t base;
    if (bid < 2048) { s = x;  d = xb;  base = (size_t)bid * 2048 + threadIdx.x * 8; }
    else           { s = wq; d = wqb; base = (size_t)(bid - 2048) * 2048 + threadIdx.x * 8; }
    f32x4 a = *(const f32x4*)(s + base);
    f32x4 b = *(const f32x4*)(s + base + 4);
    u16x8 o;
#pragma unroll
    for (int e = 0; e < 4; ++e) { o[e] = f2bf(a[e]); o[e + 4] = f2bf(b[e]); }
    *(u16x8*)(d + base) = o;
}

// ---------------------------------------------------------------------------
// M[h,j,f] = 0.125 * sum_e Wq[e, h*64+j] * Wv[e, h*64+f]
// grid (8 jgroups, 16 h): each block does 8 j-rows sharing one Wv column read.
__global__ __launch_bounds__(256) void k_precomp_M(
    const float* __restrict__ Wq, const float* __restrict__ Wv, float* __restrict__ M) {
    __shared__ float red[4][8][64];
    const int tid = threadIdx.x;
    const int f = tid & 63, ks = tid >> 6;
    const int jg = blockIdx.x, h = blockIdx.y;
    const float* vcol = Wv + h * DHEAD + f;
    const float* qcol = Wq + h * DHEAD + jg * 8;
    float acc[8];
#pragma unroll
    for (int jj = 0; jj < 8; ++jj) acc[jj] = 0.f;
    const int e0 = ks * 256;
    for (int e = e0; e < e0 + 256; ++e) {
        float v = vcol[(size_t)e * D_DIM];
        const float* qr = qcol + (size_t)e * D_DIM;
#pragma unroll
        for (int jj = 0; jj < 8; ++jj) acc[jj] += qr[jj] * v;
    }
#pragma unroll
    for (int jj = 0; jj < 8; ++jj) red[ks][jj][f] = acc[jj];
    __syncthreads();
    for (int t = tid; t < 512; t += 256) {
        int jj = t >> 6, ff = t & 63;
        float s = red[0][jj][ff] + red[1][jj][ff] + red[2][jj][ff] + red[3][jj][ff];
        M[((size_t)(h * 64 + jg * 8 + jj)) * 64 + ff] = s * 0.125f;
    }
}

// ---------------------------------------------------------------------------
// W2[o, h*64+j] = sum_f M[h,j,f] * Wout[o, h*64+f]   (bf16 out)
__global__ __launch_bounds__(256) void k_precomp_W2(
    const float* __restrict__ M, const float* __restrict__ Wout, u16* __restrict__ W2) {
    __shared__ float Ms[64][65];
    __shared__ float Ws[64][65];
    const int tid = threadIdx.x;
    const int ob = blockIdx.x, h = blockIdx.y;
    {
        int rr = tid >> 2, seg = tid & 3;
        const float* ms = M + ((size_t)(h * 64 + rr)) * 64 + seg * 16;
        const float* ws = Wout + (size_t)(ob * 64 + rr) * D_DIM + h * DHEAD + seg * 16;
#pragma unroll
        for (int e = 0; e < 16; ++e) {
            Ms[rr][seg * 16 + e] = ms[e];
            Ws[rr][seg * 16 + e] = ws[e];
        }
    }
    __syncthreads();
    int j = tid & 63, o0 = (tid >> 6) * 16;
    for (int oo = o0; oo < o0 + 16; ++oo) {
        float acc = 0.f;
#pragma unroll
        for (int f = 0; f < 64; ++f) acc += Ms[j][f] * Ws[oo][f];
        W2[(size_t)(ob * 64 + oo) * D_DIM + h * DHEAD + j] = f2bf(acc);
    }
}

// ---------------------------------------------------------------------------
// Q projection (pure bf16 GEMM) + side-products:
//   Qbf[s,d], QT[b,h,d,s], sq05[b,h,s] = 0.125*log2e*||q_h||^2 (mask->1e30)
__global__ __launch_bounds__(256) void k_qproj(
    const u16* __restrict__ xb, const u16* __restrict__ wqb,
    const float* __restrict__ bq, const int* __restrict__ mask,
    u16* __restrict__ Qbf, u16* __restrict__ QT, float* __restrict__ sq05) {
    __shared__ u16 Al[128][36];
    __shared__ u16 Bl[128][36];
    const int tid = threadIdx.x, lane = tid & 63, w = tid >> 6;
    const int wm = w & 1, wn = w >> 1;
    const int col16 = lane & 15, quad = lane >> 4;
    const int bm = blockIdx.x, bn = blockIdx.y;

    f32x4 acc[4][4];
    const f32x4 z4 = {0.f, 0.f, 0.f, 0.f};
#pragma unroll
    for (int i = 0; i < 4; ++i)
#pragma unroll
        for (int j = 0; j < 4; ++j) acc[i][j] = z4;

    const int r = tid >> 1, hf = tid & 1;
    const u16* pa = xb + (size_t)(bm * 128 + r) * D_DIM + hf * 16;
    const u16* pb = wqb + (size_t)(bn * 128 + r) * D_DIM + hf * 16;

    u16x8 ra0 = *(const u16x8*)(pa),     ra1 = *(const u16x8*)(pa + 8);
    u16x8 rb0 = *(const u16x8*)(pb),     rb1 = *(const u16x8*)(pb + 8);

    for (int k0 = 0; k0 < D_DIM; k0 += 32) {
        __syncthreads();
        *(u16x8*)&Al[r][hf * 16]     = ra0;
        *(u16x8*)&Al[r][hf * 16 + 8] = ra1;
        *(u16x8*)&Bl[r][hf * 16]     = rb0;
        *(u16x8*)&Bl[r][hf * 16 + 8] = rb1;
        __syncthreads();
        if (k0 + 32 < D_DIM) {
            ra0 = *(const u16x8*)(pa + k0 + 32); ra1 = *(const u16x8*)(pa + k0 + 40);
            rb0 = *(const u16x8*)(pb + k0 + 32); rb1 = *(const u16x8*)(pb + k0 + 40);
        }
        bf16x8 af[4];
#pragma unroll
        for (int mt = 0; mt < 4; ++mt)
            af[mt] = *(const bf16x8*)&Al[wm * 64 + mt * 16 + col16][quad * 8];
#pragma unroll
        for (int nt = 0; nt < 4; ++nt) {
            bf16x8 bfr = *(const bf16x8*)&Bl[wn * 64 + nt * 16 + col16][quad * 8];
#pragma unroll
            for (int mt = 0; mt < 4; ++mt)
                acc[mt][nt] = MFMA16(af[mt], bfr, acc[mt][nt]);
        }
    }

    const int h = bn * 2 + wn;
    f32x4 ssum[4];
#pragma unroll
    for (int mt = 0; mt < 4; ++mt) ssum[mt] = z4;

#pragma unroll
    for (int nt = 0; nt < 4; ++nt) {
        int col = bn * 128 + wn * 64 + nt * 16 + col16;
        int dloc = nt * 16 + col16;
        float bqv = bq[col];
#pragma unroll
        for (int mt = 0; mt < 4; ++mt) {
            int row0 = bm * 128 + wm * 64 + mt * 16 + quad * 4;
            int b = row0 >> 11, smod0 = row0 & 2047;
            u16x4 pk;
#pragma unroll
            for (int rr = 0; rr < 4; ++rr) {
                float qv = acc[mt][nt][rr] + bqv;
                ssum[mt][rr] += qv * qv;
                u16 bv = f2bf(qv);
                pk[rr] = bv;
                Qbf[(size_t)(row0 + rr) * D_DIM + col] = bv;
            }
            *(u16x4*)(QT + ((size_t)(b * NH + h) * DHEAD + dloc) * S_LEN + smod0) = pk;
        }
    }
#pragma unroll
    for (int mt = 0; mt < 4; ++mt) {
        int row0 = bm * 128 + wm * 64 + mt * 16 + quad * 4;
        int b = row0 >> 11, smod0 = row0 & 2047;
#pragma unroll
        for (int rr = 0; rr < 4; ++rr) {
            float v = ssum[mt][rr];
            v += __shfl_xor(v, 1); v += __shfl_xor(v, 2);
            v += __shfl_xor(v, 4); v += __shfl_xor(v, 8);
            if (col16 == 0) {
                int sidx = smod0 + rr;
                float out = mask[b * S_LEN + sidx] ? v * C_SQ : 1e30f;
                sq05[((size_t)(b * NH + h)) * S_LEN + sidx] = out;
            }
        }
    }
}

// ---------------------------------------------------------------------------
// Fused L2 attention. Block = (b, h, q-tile 128). 4 waves x (32 q-rows, 128 k).
__global__ __launch_bounds__(256, 2) void k_flash(
    const u16* __restrict__ Qbf, const u16* __restrict__ QT,
    const float* __restrict__ sq05, u16* __restrict__ attnO) {
    __shared__ u16 Kt[128][68];
    __shared__ u16 KtT[64][132];
    __shared__ u16 Ptw[4][32][34];
    __shared__ float sql[128];

    const int tid = threadIdx.x, lane = tid & 63, w = tid >> 6;
    const int col16 = lane & 15, quad = lane >> 4;
    const int qt = blockIdx.x & 15;
    const int h = (blockIdx.x >> 4) & 15;
    const int b = blockIdx.x >> 8;
    const u16* qbase = Qbf + (size_t)b * S_LEN * D_DIM + h * DHEAD;
    const u16* qtbase = QT + ((size_t)(b * NH + h)) * DHEAD * S_LEN;
    const float* sqb = sq05 + ((size_t)(b * NH + h)) * S_LEN;

    bf16x8 af[2][2];
#pragma unroll
    for (int mt = 0; mt < 2; ++mt)
#pragma unroll
        for (int k0 = 0; k0 < 2; ++k0)
            af[mt][k0] = *(const bf16x8*)(qbase +
                (size_t)(qt * 128 + w * 32 + mt * 16 + col16) * D_DIM + k0 * 32 + quad * 8);

    const int kr = tid >> 1, ks = tid & 1;
    const int td = tid >> 2, ts = tid & 3;
    const u16* ksrc = qbase + (size_t)kr * D_DIM + ks * 32;
    const u16* tsrc = qtbase + (size_t)td * S_LEN + ts * 32;

    u16x8 pk[4], pt[4];
    float sv = 0.f;
    {
#pragma unroll
        for (int i = 0; i < 4; ++i) pk[i] = *(const u16x8*)(ksrc + i * 8);
#pragma unroll
        for (int i = 0; i < 4; ++i) pt[i] = *(const u16x8*)(tsrc + i * 8);
        if (tid < 128) sv = sqb[tid];
    }

    f32x4 Oacc[2][4], lacc[2];
    const f32x4 z4 = {0.f, 0.f, 0.f, 0.f};
#pragma unroll
    for (int m = 0; m < 2; ++m) {
        lacc[m] = z4;
#pragma unroll
        for (int i = 0; i < 4; ++i) Oacc[m][i] = z4;
    }
    bf16x8 ones;
    {
        union { u16x8 u; bf16x8 b; } cv;
#pragma unroll
        for (int e = 0; e < 8; ++e) cv.u[e] = 0x3F80;
        ones = cv.b;
    }

    for (int j = 0; j < S_LEN / 128; ++j) {
        __syncthreads();
#pragma unroll
        for (int i = 0; i < 4; ++i) *(u16x8*)&Kt[kr][ks * 32 + i * 8] = pk[i];
#pragma unroll
        for (int i = 0; i < 4; ++i) *(u16x8*)&KtT[td][ts * 32 + i * 8] = pt[i];
        if (tid < 128) sql[tid] = sv;
        __syncthreads();

        int jn = (j + 1) & 15;
        {
            const u16* kn = ksrc + (size_t)jn * 128 * D_DIM;
            const u16* tn = tsrc + (size_t)jn * 128;
#pragma unroll
            for (int i = 0; i < 4; ++i) pk[i] = *(const u16x8*)(kn + i * 8);
#pragma unroll
            for (int i = 0; i < 4; ++i) pt[i] = *(const u16x8*)(tn + i * 8);
            if (tid < 128) sv = sqb[jn * 128 + tid];
        }

        f32x4 sacc[2][8];
#pragma unroll
        for (int m = 0; m < 2; ++m)
#pragma unroll
            for (int n = 0; n < 8; ++n) sacc[m][n] = z4;
#pragma unroll
        for (int k0 = 0; k0 < 2; ++k0) {
#pragma unroll
            for (int n = 0; n < 8; ++n) {
                bf16x8 bb = *(const bf16x8*)&Kt[n * 16 + col16][k0 * 32 + quad * 8];
                sacc[0][n] = MFMA16(af[0][k0], bb, sacc[0][n]);
                sacc[1][n] = MFMA16(af[1][k0], bb, sacc[1][n]);
            }
        }
        float sq2[8];
#pragma unroll
        for (int n = 0; n < 8; ++n) sq2[n] = sql[n * 16 + col16];

#pragma unroll
        for (int kt = 0; kt < 4; ++kt) {
#pragma unroll
            for (int m = 0; m < 2; ++m)
#pragma unroll
                for (int nn = 0; nn < 2; ++nn) {
                    int n = kt * 2 + nn;
#pragma unroll
                    for (int rr = 0; rr < 4; ++rr) {
                        float p = EXP2(fmaf(sacc[m][n][rr], C_QK, -sq2[n]));
                        union { float f; u16 h[2]; } cc; cc.f = p;
                        Ptw[w][m * 16 + quad * 4 + rr][nn * 16 + col16] = cc.h[1];
                    }
                }
            bf16x8 pa0 = *(const bf16x8*)&Ptw[w][col16][quad * 8];
            bf16x8 pa1 = *(const bf16x8*)&Ptw[w][16 + col16][quad * 8];
            lacc[0] = MFMA16(pa0, ones, lacc[0]);
            lacc[1] = MFMA16(pa1, ones, lacc[1]);
#pragma unroll
            for (int no = 0; no < 4; ++no) {
                bf16x8 vb = *(const bf16x8*)&KtT[no * 16 + col16][kt * 32 + quad * 8];
                Oacc[0][no] = MFMA16(pa0, vb, Oacc[0][no]);
                Oacc[1][no] = MFMA16(pa1, vb, Oacc[1][no]);
            }
        }
    }

    u16* obase = attnO + (size_t)b * S_LEN * D_DIM + h * DHEAD;
#pragma unroll
    for (int m = 0; m < 2; ++m) {
        f32x4 rinv;
#pragma unroll
        for (int rr = 0; rr < 4; ++rr) rinv[rr] = 1.f / lacc[m][rr];
#pragma unroll
        for (int no = 0; no < 4; ++no)
#pragma unroll
            for (int rr = 0; rr < 4; ++rr) {
                int srow = qt * 128 + w * 32 + m * 16 + quad * 4 + rr;
                obase[(size_t)srow * D_DIM + no * 16 + col16] =
                    f2bf(Oacc[m][no][rr] * rinv[rr]);
            }
    }
}

// ---------------------------------------------------------------------------
// Output GEMM: out[s,o] = x[s,o] + bout[o] + sum_c attnO[s,c] * W2[o,c]
__global__ __launch_bounds__(256) void k_oproj(
    const u16* __restrict__ attnO, const u16* __restrict__ W2,
    const float* __restrict__ x, const float* __restrict__ bout, float* __restrict__ out) {
    __shared__ u16 Al[128][36];
    __shared__ u16 Bl[128][36];
    const int tid = threadIdx.x, lane = tid & 63, w = tid >> 6;
    const int wm = w & 1, wn = w >> 1;
    const int col16 = lane & 15, quad = lane >> 4;
    const int bm = blockIdx.x, bn = blockIdx.y;

    f32x4 acc[4][4];
    const f32x4 z4 = {0.f, 0.f, 0.f, 0.f};
#pragma unroll
    for (int i = 0; i < 4; ++i)
#pragma unroll
        for (int j = 0; j < 4; ++j) acc[i][j] = z4;

    const int r = tid >> 1, hf = tid & 1;
    const u16* pa = attnO + (size_t)(bm * 128 + r) * D_DIM + hf * 16;
    const u16* pb = W2 + (size_t)(bn * 128 + r) * D_DIM + hf * 16;

    u16x8 ra0 = *(const u16x8*)(pa),     ra1 = *(const u16x8*)(pa + 8);
    u16x8 rb0 = *(const u16x8*)(pb),     rb1 = *(const u16x8*)(pb + 8);

    for (int k0 = 0; k0 < D_DIM; k0 += 32) {
        __syncthreads();
        *(u16x8*)&Al[r][hf * 16]     = ra0;
        *(u16x8*)&Al[r][hf * 16 + 8] = ra1;
        *(u16x8*)&Bl[r][hf * 16]     = rb0;
        *(u16x8*)&Bl[r][hf * 16 + 8] = rb1;
        __syncthreads();
        if (k0 + 32 < D_DIM) {
            ra0 = *(const u16x8*)(pa + k0 + 32); ra1 = *(const u16x8*)(pa + k0 + 40);
            rb0 = *(const u16x8*)(pb + k0 + 32); rb1 = *(const u16x8*)(pb + k0 + 40);
        }
        bf16x8 af[4];
#pragma unroll
        for (int mt = 0; mt < 4; ++mt)
            af[mt] = *(const bf16x8*)&Al[wm * 64 + mt * 16 + col16][quad * 8];
#pragma unroll
        for (int nt = 0; nt < 4; ++nt) {
            bf16x8 bfr = *(const bf16x8*)&Bl[wn * 64 + nt * 16 + col16][quad * 8];
#pragma unroll
            for (int mt = 0; mt < 4; ++mt)
                acc[mt][nt] = MFMA16(af[mt], bfr, acc[mt][nt]);
        }
    }
#pragma unroll
    for (int nt = 0; nt < 4; ++nt) {
        int col = bn * 128 + wn * 64 + nt * 16 + col16;
        float bv = bout[col];
#pragma unroll
        for (int mt = 0; mt < 4; ++mt) {
            int row0 = bm * 128 + wm * 64 + mt * 16 + quad * 4;
#pragma unroll
            for (int rr = 0; rr < 4; ++rr) {
                size_t idx = (size_t)(row0 + rr) * D_DIM + col;
                out[idx] = acc[mt][nt][rr] + x[idx] + bv;
            }
        }
    }
}

// ---------------------------------------------------------------------------
extern "C" void kernel_launch(void* const* d_in, const int* in_sizes, int n_in,
                              void* d_out, int out_size, void* d_ws, size_t ws_size,
                              hipStream_t stream) {
    const float* x    = (const float*)d_in[0];
    const float* Wq   = (const float*)d_in[1];
    const float* bq   = (const float*)d_in[2];
    const float* Wv   = (const float*)d_in[3];
    const float* Wout = (const float*)d_in[4];
    const float* bout = (const float*)d_in[5];
    const int*   mask = (const int*)d_in[6];
    float* out = (float*)d_out;

    char* ws = (char*)d_ws;
    u16*   Qbf   = (u16*)(ws);                         // 8 MB
    u16*   QT    = (u16*)(ws + (8u << 20));            // 8 MB
    u16*   W2    = (u16*)(ws + (16u << 20));           // 2 MB
    u16*   xb    = (u16*)(ws + (18u << 20));           // 8 MB (reused as attnO)
    u16*   wqb   = (u16*)(ws + (26u << 20));           // 2 MB
    float* Mbuf  = (float*)(ws + (28u << 20));         // 256 KB
    float* sq05  = (float*)(ws + (28u << 20) + (256u << 10)); // 256 KB
    u16*   attnO = xb;   // xb dead after k_qproj; flash writes attnO after

    k_cvt<<<dim3(2560), dim3(256), 0, stream>>>(x, Wq, xb, wqb);
    k_precomp_M<<<dim3(8, 16), dim3(256), 0, stream>>>(Wq, Wv, Mbuf);
    k_precomp_W2<<<dim3(16, 16), dim3(256), 0, stream>>>(Mbuf, Wout, W2);
    k_qproj<<<dim3(32, 8), dim3(256), 0, stream>>>(xb, wqb, bq, mask, Qbf, QT, sq05);
    k_flash<<<dim3(512), dim3(256), 0, stream>>>(Qbf, QT, sq05, attnO);
    k_oproj<<<dim3(32, 8), dim3(256), 0, stream>>>(attnO, W2, x, bout, out);
}